// Round 1
// baseline (884.867 us; speedup 1.0000x reference)
//
#include <hip/hip_runtime.h>
#include <hip/hip_bf16.h>

typedef __attribute__((ext_vector_type(8))) short short8;
typedef __attribute__((ext_vector_type(4))) float floatx4;

__device__ __forceinline__ unsigned short f2bf(float f) {
    // round-to-nearest-even fp32 -> bf16
    unsigned int u = __builtin_bit_cast(unsigned int, f);
    u += 0x7fffu + ((u >> 16) & 1u);
    return (unsigned short)(u >> 16);
}

#define BM 128
#define BN 128
#define BK 64
#define LDSS 72  // 64 + 8 pad: balances lanes across b128 bank-chunk slots

// C = A @ B^T (both row-major, K contiguous), bf16 MFMA 16x16x32, fp32 accum.
// IN_F32: inputs fp32 (converted to bf16 during staging); else bf16 (ushort).
// OUT_BF16: store bf16, else fp32. bias_mode: 0 none, 1 per-col, 2 per-row.
template<bool IN_F32, bool OUT_BF16>
__global__ void gemm_kernel(const void* __restrict__ Ap, const void* __restrict__ Bp,
                            void* __restrict__ Op, const float* __restrict__ bias,
                            int bias_mode, int K, int lda, int ldb, int ldo,
                            long long aBS, long long bBS, long long oBS, float scale)
{
    __shared__ __align__(16) unsigned short As[BM][LDSS];
    __shared__ __align__(16) unsigned short Bs[BN][LDSS];

    const int t = threadIdx.x;
    const int z = blockIdx.z;
    const size_t m0 = (size_t)blockIdx.x * BM;
    const size_t n0 = (size_t)blockIdx.y * BN;

    const int lane = t & 63;
    const int lq = lane >> 4, lr = lane & 15;
    const int w = t >> 6;
    const int wr = w >> 1, wc = w & 1;

    floatx4 acc[4][4];
#pragma unroll
    for (int i = 0; i < 4; ++i)
#pragma unroll
        for (int j = 0; j < 4; ++j)
            acc[i][j] = (floatx4){0.f, 0.f, 0.f, 0.f};

    const int nk = K / BK;
    for (int kt = 0; kt < nk; ++kt) {
        const int k0 = kt * BK;
        if (IN_F32) {
            const float* Af = (const float*)Ap + (size_t)z * aBS;
            const float* Bf = (const float*)Bp + (size_t)z * bBS;
            const int c4 = t & 15, r0 = t >> 4;
#pragma unroll
            for (int s = 0; s < 8; ++s) {
                const int row = r0 + s * 16;
                float4 fa = *(const float4*)(Af + (m0 + row) * (size_t)lda + k0 + c4 * 4);
                float4 fb = *(const float4*)(Bf + (n0 + row) * (size_t)ldb + k0 + c4 * 4);
                ushort4 ha = {f2bf(fa.x), f2bf(fa.y), f2bf(fa.z), f2bf(fa.w)};
                ushort4 hb = {f2bf(fb.x), f2bf(fb.y), f2bf(fb.z), f2bf(fb.w)};
                *(ushort4*)&As[row][c4 * 4] = ha;
                *(ushort4*)&Bs[row][c4 * 4] = hb;
            }
        } else {
            const unsigned short* Ab = (const unsigned short*)Ap + (size_t)z * aBS;
            const unsigned short* Bb = (const unsigned short*)Bp + (size_t)z * bBS;
            const int c8 = t & 7, r0 = t >> 3;
#pragma unroll
            for (int s = 0; s < 4; ++s) {
                const int row = r0 + s * 32;
                short8 va = *(const short8*)(Ab + (m0 + row) * (size_t)lda + k0 + c8 * 8);
                short8 vb = *(const short8*)(Bb + (n0 + row) * (size_t)ldb + k0 + c8 * 8);
                *(short8*)&As[row][c8 * 8] = va;
                *(short8*)&Bs[row][c8 * 8] = vb;
            }
        }
        __syncthreads();
#pragma unroll
        for (int kk = 0; kk < 2; ++kk) {
            short8 af[4], bfr[4];
#pragma unroll
            for (int mi = 0; mi < 4; ++mi)
                af[mi] = *(const short8*)&As[wr * 64 + mi * 16 + lr][kk * 32 + lq * 8];
#pragma unroll
            for (int ni = 0; ni < 4; ++ni)
                bfr[ni] = *(const short8*)&Bs[wc * 64 + ni * 16 + lr][kk * 32 + lq * 8];
#pragma unroll
            for (int mi = 0; mi < 4; ++mi)
#pragma unroll
                for (int ni = 0; ni < 4; ++ni)
                    acc[mi][ni] = __builtin_amdgcn_mfma_f32_16x16x32_bf16(af[mi], bfr[ni], acc[mi][ni], 0, 0, 0);
        }
        __syncthreads();
    }

    // epilogue: D row = (lane>>4)*4 + reg, col = lane&15 (verified gfx950 C/D map)
#pragma unroll
    for (int mi = 0; mi < 4; ++mi) {
#pragma unroll
        for (int ni = 0; ni < 4; ++ni) {
            const size_t col = n0 + wc * 64 + ni * 16 + lr;
            const float cb = (bias_mode == 1) ? bias[col] : 0.f;
            floatx4 v = acc[mi][ni];
#pragma unroll
            for (int r = 0; r < 4; ++r) {
                const size_t row = m0 + wr * 64 + mi * 16 + lq * 4 + r;
                float val = v[r] * scale + cb;
                if (bias_mode == 2) val += bias[row];
                if (OUT_BF16)
                    ((unsigned short*)Op)[(size_t)z * oBS + row * (size_t)ldo + col] = f2bf(val);
                else
                    ((float*)Op)[(size_t)z * oBS + row * (size_t)ldo + col] = val;
            }
        }
    }
}

// One wave per row of S (2048 fp32). Adds mask, fp32 softmax, writes P bf16
// in place over the row's own fp32 storage (row stride stays 4096 bf16 elems).
__global__ void softmax_kernel(float* __restrict__ S, const float* __restrict__ mask, int b0)
{
    const int lane = threadIdx.x & 63;
    const int wid = threadIdx.x >> 6;
    const size_t rowid = (size_t)blockIdx.x * 4 + wid;
    const size_t bi = rowid >> 11;
    const size_t q = rowid & 2047;
    float* Srow = S + rowid * 2048;
    const float* Mrow = mask + (((size_t)b0 + bi) * 2048 + q) * 2048;

    float4 v[8];
    float mx = -3.4e38f;
#pragma unroll
    for (int i = 0; i < 8; ++i) {
        float4 s = ((const float4*)Srow)[i * 64 + lane];
        float4 m = ((const float4*)Mrow)[i * 64 + lane];
        s.x += m.x; s.y += m.y; s.z += m.z; s.w += m.w;
        v[i] = s;
        mx = fmaxf(mx, fmaxf(fmaxf(s.x, s.y), fmaxf(s.z, s.w)));
    }
#pragma unroll
    for (int off = 32; off; off >>= 1) mx = fmaxf(mx, __shfl_xor(mx, off, 64));
    float sum = 0.f;
#pragma unroll
    for (int i = 0; i < 8; ++i) {
        v[i].x = __expf(v[i].x - mx);
        v[i].y = __expf(v[i].y - mx);
        v[i].z = __expf(v[i].z - mx);
        v[i].w = __expf(v[i].w - mx);
        sum += v[i].x + v[i].y + v[i].z + v[i].w;
    }
#pragma unroll
    for (int off = 32; off; off >>= 1) sum += __shfl_xor(sum, off, 64);
    const float inv = 1.0f / sum;

    unsigned short* Prow = (unsigned short*)Srow;
#pragma unroll
    for (int i = 0; i < 8; ++i) {
        ushort4 h = {f2bf(v[i].x * inv), f2bf(v[i].y * inv),
                     f2bf(v[i].z * inv), f2bf(v[i].w * inv)};
        ((ushort4*)Prow)[i * 64 + lane] = h;
    }
}

extern "C" void kernel_launch(void* const* d_in, const int* in_sizes, int n_in,
                              void* d_out, int out_size, void* d_ws, size_t ws_size,
                              hipStream_t stream)
{
    const float* x    = (const float*)d_in[0];
    const float* mask = (const float*)d_in[1];
    const float* Wq   = (const float*)d_in[2];
    const float* bq   = (const float*)d_in[3];
    const float* Wk   = (const float*)d_in[4];
    const float* bk   = (const float*)d_in[5];
    const float* Wv   = (const float*)d_in[6];
    const float* bv   = (const float*)d_in[7];
    float* out = (float*)d_out;

    const size_t MB = 1ull << 20;
    char* ws = (char*)d_ws;
    unsigned short* Qb = (unsigned short*)(ws);            // 16384 x 1024 bf16 (32MB)
    unsigned short* Kb = (unsigned short*)(ws + 32 * MB);  // 16384 x 1024 bf16
    unsigned short* Vt = (unsigned short*)(ws + 64 * MB);  // 1024 x 16384 bf16 (V^T)
    float* Sb = (float*)(ws + 96 * MB);                    // g x 2048 x 2048 f32

    size_t avail = (ws_size > 96 * MB) ? (ws_size - 96 * MB) : 0;
    int g = (int)(avail / (16 * MB));
    if (g < 1) g = 1;
    if (g > 8) g = 8;

    dim3 blk(256, 1, 1);

    // Q = x @ Wq^T + bq  -> Qb (16384,1024) bf16
    gemm_kernel<true, true><<<dim3(128, 8, 1), blk, 0, stream>>>(
        x, Wq, Qb, bq, 1, 1024, 1024, 1024, 1024, 0LL, 0LL, 0LL, 1.0f);
    // K = x @ Wk^T + bk  -> Kb
    gemm_kernel<true, true><<<dim3(128, 8, 1), blk, 0, stream>>>(
        x, Wk, Kb, bk, 1, 1024, 1024, 1024, 1024, 0LL, 0LL, 0LL, 1.0f);
    // V^T = Wv @ x^T + bv (per-row bias) -> Vt (1024,16384)
    gemm_kernel<true, true><<<dim3(8, 128, 1), blk, 0, stream>>>(
        Wv, x, Vt, bv, 2, 1024, 1024, 1024, 16384, 0LL, 0LL, 0LL, 1.0f);

    const float sscale = 0.03125f; // 1/sqrt(1024)
    for (int b0 = 0; b0 < 8; b0 += g) {
        const int gb = (8 - b0 < g) ? (8 - b0) : g;
        // S = (Q @ K^T) * scale   (per batch in group), fp32 into Sb
        gemm_kernel<false, false><<<dim3(16, 16, gb), blk, 0, stream>>>(
            Qb + (size_t)b0 * 2048 * 1024, Kb + (size_t)b0 * 2048 * 1024, Sb,
            (const float*)nullptr, 0, 1024, 1024, 1024, 2048,
            2048LL * 1024, 2048LL * 1024, 2048LL * 2048, sscale);
        // softmax rows (adds mask), P bf16 in place (row stride 4096 bf16)
        softmax_kernel<<<dim3(gb * 512, 1, 1), blk, 0, stream>>>(Sb, mask, b0);
        // O = P @ V  (B-operand = Vt rows, K-contiguous)
        gemm_kernel<false, false><<<dim3(16, 8, gb), blk, 0, stream>>>(
            (const unsigned short*)Sb, Vt + (size_t)b0 * 2048,
            out + (size_t)b0 * 2048 * 1024, (const float*)nullptr, 0,
            2048, 4096, 16384, 1024,
            2048LL * 4096, 2048LL, 2048LL * 1024, 1.0f);
    }
}

// Round 2
// 611.183 us; speedup vs baseline: 1.4478x; 1.4478x over previous
//
#include <hip/hip_runtime.h>
#include <hip/hip_bf16.h>

typedef __attribute__((ext_vector_type(8))) short short8;
typedef __attribute__((ext_vector_type(4))) float floatx4;

__device__ __forceinline__ unsigned short f2bf(float f) {
    unsigned int u = __builtin_bit_cast(unsigned int, f);
    u += 0x7fffu + ((u >> 16) & 1u);
    return (unsigned short)(u >> 16);
}

__device__ __forceinline__ void gl_lds16(const unsigned short* g, unsigned short* l) {
    __builtin_amdgcn_global_load_lds(
        (const __attribute__((address_space(1))) unsigned int*)(const void*)g,
        (__attribute__((address_space(3))) unsigned int*)(void*)l,
        16, 0, 0);
}

#define BM 128
#define BN 128
#define BK 64

// C = A @ B^T, A (M,K) lda, B (N,K) ldb, both bf16 K-contiguous row-major.
// m97 structure: global_load_lds w=16 staging, linear LDS, 2-barrier K-loop.
// bias_mode: 0 none, 1 per-col (bias[col]), 2 per-row (bias[row]).
template<bool OUT_BF16>
__global__ void gemm_bt(const unsigned short* __restrict__ A,
                        const unsigned short* __restrict__ B,
                        void* __restrict__ O, const float* __restrict__ bias,
                        int bias_mode, int K, int lda, int ldb, int ldo,
                        long long aBS, long long bBS, long long oBS,
                        float scale, int nbx)
{
    __shared__ __align__(16) unsigned short As[BM * BK]; // 16 KB, [128][64] linear
    __shared__ __align__(16) unsigned short Bs[BN * BK];

    const int t = threadIdx.x;
    const int z = blockIdx.z;

    // T1: bijective XCD swizzle (grid.x always a multiple of 8 here)
    const int nwg = gridDim.x;
    const int cpx = nwg >> 3;
    const int swz = (blockIdx.x & 7) * cpx + (blockIdx.x >> 3);
    const int bx = swz % nbx, by = swz / nbx;
    const size_t m0 = (size_t)bx * BM;
    const size_t n0 = (size_t)by * BN;

    const unsigned short* Az = A + (size_t)z * aBS;
    const unsigned short* Bz = B + (size_t)z * bBS;

    const int lane = t & 63;
    const int w = t >> 6;            // wave 0..3
    const int lq = lane >> 4, lr = lane & 15;
    const int wr = w >> 1, wc = w & 1;

    // staging coords: thread t loads 16B; row = t>>3, col elem = (t&7)*8
    const int srow = t >> 3;
    const int scol = (t & 7) * 8;
    unsigned short* lA = As + w * 512;  // wave-uniform LDS base (w*1024 bytes)
    unsigned short* lB = Bs + w * 512;

    floatx4 acc[4][4];
#pragma unroll
    for (int i = 0; i < 4; ++i)
#pragma unroll
        for (int j = 0; j < 4; ++j)
            acc[i][j] = (floatx4){0.f, 0.f, 0.f, 0.f};

    for (int kt = 0; kt < K; kt += BK) {
        const unsigned short* ga = Az + (m0 + srow) * (size_t)lda + kt + scol;
        const unsigned short* gb = Bz + (n0 + srow) * (size_t)ldb + kt + scol;
#pragma unroll
        for (int s = 0; s < 4; ++s) {
            gl_lds16(ga + (size_t)s * 32 * lda, lA + s * 2048);
            gl_lds16(gb + (size_t)s * 32 * ldb, lB + s * 2048);
        }
        __syncthreads();  // drains vmcnt -> tiles ready
#pragma unroll
        for (int kk = 0; kk < 2; ++kk) {
            short8 af[4], bf[4];
#pragma unroll
            for (int mi = 0; mi < 4; ++mi)
                af[mi] = *(const short8*)&As[(wr * 64 + mi * 16 + lr) * BK + kk * 32 + lq * 8];
#pragma unroll
            for (int ni = 0; ni < 4; ++ni)
                bf[ni] = *(const short8*)&Bs[(wc * 64 + ni * 16 + lr) * BK + kk * 32 + lq * 8];
#pragma unroll
            for (int mi = 0; mi < 4; ++mi)
#pragma unroll
                for (int ni = 0; ni < 4; ++ni)
                    acc[mi][ni] = __builtin_amdgcn_mfma_f32_16x16x32_bf16(af[mi], bf[ni], acc[mi][ni], 0, 0, 0);
        }
        __syncthreads();  // all reads done before next stage overwrites
    }

    // epilogue: D row = (lane>>4)*4 + reg, col = lane&15
#pragma unroll
    for (int mi = 0; mi < 4; ++mi) {
#pragma unroll
        for (int ni = 0; ni < 4; ++ni) {
            const size_t col = n0 + wc * 64 + ni * 16 + lr;
            const float cb = (bias_mode == 1) ? bias[col] : 0.f;
            floatx4 v = acc[mi][ni];
#pragma unroll
            for (int r = 0; r < 4; ++r) {
                const size_t row = m0 + wr * 64 + mi * 16 + lq * 4 + r;
                float val = v[r] * scale + cb;
                if (bias_mode == 2) val += bias[row];
                if (OUT_BF16)
                    ((unsigned short*)O)[(size_t)z * oBS + row * (size_t)ldo + col] = f2bf(val);
                else
                    ((float*)O)[(size_t)z * oBS + row * (size_t)ldo + col] = val;
            }
        }
    }
}

// fp32 -> bf16 vectorized conversion, grid-stride
__global__ void cvt_f2b(const float4* __restrict__ src, ushort4* __restrict__ dst, int n4)
{
    int i = blockIdx.x * blockDim.x + threadIdx.x;
    const int stride = gridDim.x * blockDim.x;
    for (; i < n4; i += stride) {
        float4 f = src[i];
        dst[i] = (ushort4){f2bf(f.x), f2bf(f.y), f2bf(f.z), f2bf(f.w)};
    }
}

// One wave per row of S (2048 fp32): add mask, fp32 softmax, write P bf16 in
// place over the row's own fp32 storage (bf16 row stride = 4096 elements).
__global__ void softmax_kernel(float* __restrict__ S, const float* __restrict__ mask, int b0)
{
    const int lane = threadIdx.x & 63;
    const int wid = threadIdx.x >> 6;
    const size_t rowid = (size_t)blockIdx.x * 4 + wid;
    const size_t bi = rowid >> 11;
    const size_t q = rowid & 2047;
    float* Srow = S + rowid * 2048;
    const float* Mrow = mask + (((size_t)b0 + bi) * 2048 + q) * 2048;

    float4 v[8];
    float mx = -3.4e38f;
#pragma unroll
    for (int i = 0; i < 8; ++i) {
        float4 s = ((const float4*)Srow)[i * 64 + lane];
        float4 m = ((const float4*)Mrow)[i * 64 + lane];
        s.x += m.x; s.y += m.y; s.z += m.z; s.w += m.w;
        v[i] = s;
        mx = fmaxf(mx, fmaxf(fmaxf(s.x, s.y), fmaxf(s.z, s.w)));
    }
#pragma unroll
    for (int off = 32; off; off >>= 1) mx = fmaxf(mx, __shfl_xor(mx, off, 64));
    float sum = 0.f;
#pragma unroll
    for (int i = 0; i < 8; ++i) {
        v[i].x = __expf(v[i].x - mx);
        v[i].y = __expf(v[i].y - mx);
        v[i].z = __expf(v[i].z - mx);
        v[i].w = __expf(v[i].w - mx);
        sum += v[i].x + v[i].y + v[i].z + v[i].w;
    }
#pragma unroll
    for (int off = 32; off; off >>= 1) sum += __shfl_xor(sum, off, 64);
    const float inv = 1.0f / sum;

    unsigned short* Prow = (unsigned short*)Srow;
#pragma unroll
    for (int i = 0; i < 8; ++i) {
        ushort4 h = {f2bf(v[i].x * inv), f2bf(v[i].y * inv),
                     f2bf(v[i].z * inv), f2bf(v[i].w * inv)};
        ((ushort4*)Prow)[i * 64 + lane] = h;
    }
}

extern "C" void kernel_launch(void* const* d_in, const int* in_sizes, int n_in,
                              void* d_out, int out_size, void* d_ws, size_t ws_size,
                              hipStream_t stream)
{
    const float* x    = (const float*)d_in[0];
    const float* mask = (const float*)d_in[1];
    const float* Wq   = (const float*)d_in[2];
    const float* bq   = (const float*)d_in[3];
    const float* Wk   = (const float*)d_in[4];
    const float* bk   = (const float*)d_in[5];
    const float* Wv   = (const float*)d_in[6];
    const float* bv   = (const float*)d_in[7];
    float* out = (float*)d_out;

    const size_t MB = 1ull << 20;
    char* ws = (char*)d_ws;
    unsigned short* Qb  = (unsigned short*)(ws);             // 16384x1024 bf16 (32MB)
    unsigned short* Kb  = (unsigned short*)(ws + 32 * MB);   // 16384x1024 bf16
    unsigned short* Vt  = (unsigned short*)(ws + 64 * MB);   // 1024x16384 bf16 (V^T)
    unsigned short* Wqb = (unsigned short*)(ws + 96 * MB);   // 1024x1024 bf16 (2MB)
    unsigned short* Wkb = (unsigned short*)(ws + 98 * MB);
    unsigned short* Wvb = (unsigned short*)(ws + 100 * MB);
    unsigned short* xb  = (unsigned short*)(ws + 102 * MB);  // 16384x1024 bf16 (32MB), dead after proj
    float* Sb = (float*)(ws + 102 * MB);                     // S reuses xb region onward

    // batch group size g in {8,4,2,1}: g*16MB of fp32 S must fit after 102MB
    size_t savail = (ws_size > 102 * MB) ? ws_size - 102 * MB : 0;
    int g = 1;
    if (savail >= 128 * MB) g = 8;
    else if (savail >= 64 * MB) g = 4;
    else if (savail >= 32 * MB) g = 2;

    dim3 blk(256, 1, 1);

    // fp32 -> bf16 conversions
    cvt_f2b<<<2048, 256, 0, stream>>>((const float4*)x, (ushort4*)xb, 16384 * 1024 / 4);
    cvt_f2b<<<512, 256, 0, stream>>>((const float4*)Wq, (ushort4*)Wqb, 1024 * 1024 / 4);
    cvt_f2b<<<512, 256, 0, stream>>>((const float4*)Wk, (ushort4*)Wkb, 1024 * 1024 / 4);
    cvt_f2b<<<512, 256, 0, stream>>>((const float4*)Wv, (ushort4*)Wvb, 1024 * 1024 / 4);

    // Q = x @ Wq^T + bq  (M=16384,N=1024,K=1024) -> Qb bf16
    gemm_bt<true><<<dim3(128 * 8, 1, 1), blk, 0, stream>>>(
        xb, Wqb, Qb, bq, 1, 1024, 1024, 1024, 1024, 0LL, 0LL, 0LL, 1.0f, 128);
    // K = x @ Wk^T + bk
    gemm_bt<true><<<dim3(128 * 8, 1, 1), blk, 0, stream>>>(
        xb, Wkb, Kb, bk, 1, 1024, 1024, 1024, 1024, 0LL, 0LL, 0LL, 1.0f, 128);
    // V^T = Wv @ x^T + bv (per-row bias) -> Vt (1024,16384)
    gemm_bt<true><<<dim3(8 * 128, 1, 1), blk, 0, stream>>>(
        Wvb, xb, Vt, bv, 2, 1024, 1024, 1024, 16384, 0LL, 0LL, 0LL, 1.0f, 8);

    const float sscale = 0.03125f; // 1/sqrt(1024)
    for (int b0 = 0; b0 < 8; b0 += g) {
        const int gb = (8 - b0 < g) ? (8 - b0) : g;
        // S = (Q @ K^T) * scale, fp32 into Sb
        gemm_bt<false><<<dim3(256, 1, gb), blk, 0, stream>>>(
            Qb + (size_t)b0 * 2048 * 1024, Kb + (size_t)b0 * 2048 * 1024, Sb,
            (const float*)nullptr, 0, 1024, 1024, 1024, 2048,
            2048LL * 1024, 2048LL * 1024, 2048LL * 2048, sscale, 16);
        // softmax rows (adds mask), P bf16 in place (row stride 4096 bf16)
        softmax_kernel<<<dim3(gb * 512, 1, 1), blk, 0, stream>>>(Sb, mask, b0);
        // O = P @ V  (A = P bf16 lda=4096, B = Vt rows ldb=16384)
        gemm_bt<false><<<dim3(128, 1, gb), blk, 0, stream>>>(
            (const unsigned short*)Sb, Vt + (size_t)b0 * 2048,
            out + (size_t)b0 * 2048 * 1024, (const float*)nullptr, 0,
            2048, 4096, 16384, 1024,
            2048LL * 4096, 2048LL, 2048LL * 1024, 1.0f, 16);
    }
}

// Round 6
// 556.978 us; speedup vs baseline: 1.5887x; 1.0973x over previous
//
#include <hip/hip_runtime.h>
#include <hip/hip_bf16.h>

typedef __attribute__((ext_vector_type(8))) short short8;
typedef __attribute__((ext_vector_type(4))) float floatx4;

__device__ __forceinline__ unsigned short f2bf(float f) {
    unsigned int u = __builtin_bit_cast(unsigned int, f);
    u += 0x7fffu + ((u >> 16) & 1u);
    return (unsigned short)(u >> 16);
}

__device__ __forceinline__ void gl_lds16(const unsigned short* g, unsigned short* l) {
    __builtin_amdgcn_global_load_lds(
        (const __attribute__((address_space(1))) unsigned int*)(const void*)g,
        (__attribute__((address_space(3))) unsigned int*)(void*)l,
        16, 0, 0);
}

#define BM 256
#define BN 256
#define BK 64

// C = A @ B^T, A (M,K) lda, B (N,K) ldb, bf16 K-contiguous row-major.
// 256x256 8-phase template: 8 waves (2Mx4N), per-wave 128x64 out, BK=64,
// 128KB double-buffered LDS, counted vmcnt(4), chunk XOR-swizzle (slot = j^(row&7))
// applied on the GLOBAL source (stage) and the ds_read address (both-sides, m173).
// Stage schedule per K-tile tt (4 phases): P0: A units 0,1 of tt+1; P1: A units 2,3
// of tt+1; P2: B units 0,1 of tt+2; P3: B units 2,3 of tt+2, then vmcnt(4) ->
// newest 4 outstanding = B(tt+2); everything of tile tt+1 landed.
template<bool OUT_BF16>
__global__ __launch_bounds__(512, 2)
void gemm_bt(const unsigned short* __restrict__ A,
             const unsigned short* __restrict__ B,
             void* __restrict__ O, const float* __restrict__ bias,
             int bias_mode, int K, int lda, int ldb, int ldo,
             long long aBS, long long bBS, long long oBS,
             float scale, int nby)
{
    __shared__ __align__(16) unsigned short lds[2][2][BM * BK]; // [buf][A,B][256*64] = 128 KiB

    const int t = threadIdx.x;
    const int lane = t & 63;
    const int w = t >> 6;        // wave 0..7
    const int wr = w >> 2;       // 0..1 (M)
    const int wc = w & 3;        // 0..3 (N)
    const int lq = lane >> 4;    // 0..3
    const int lr = lane & 15;

    // T1: bijective XCD swizzle (grid.x % 8 == 0 for all our launches);
    // by = swz % nby -> consecutive blocks share the A row-panel (L2 reuse).
    const int nwg = gridDim.x;
    const int swz = (blockIdx.x & 7) * (nwg >> 3) + (blockIdx.x >> 3);
    const int by = swz % nby, bx = swz / nby;
    const size_t m0 = (size_t)bx * BM, n0 = (size_t)by * BN;

    const int z = blockIdx.z;
    const unsigned short* Az = A + (size_t)z * aBS;
    const unsigned short* Bz = B + (size_t)z * bBS;

    // staging coords: thread t covers 16B chunk t of each 64-row unit:
    // row-in-unit = t>>3, slot = t&7 holds global chunk (row, slot ^ (row&7)).
    const int srow = t >> 3;
    const int scol = ((t & 7) ^ (srow & 7)) << 3;

    floatx4 acc[8][4];
#pragma unroll
    for (int i = 0; i < 8; ++i)
#pragma unroll
        for (int j = 0; j < 4; ++j)
            acc[i][j] = (floatx4){0.f, 0.f, 0.f, 0.f};

    const int NT = K / BK;

    auto stage = [&](int mat, int u, int kt, int buf) {
        const unsigned short* g = (mat ? Bz + (n0 + u * 64 + srow) * (size_t)ldb
                                       : Az + (m0 + u * 64 + srow) * (size_t)lda) + kt + scol;
        gl_lds16(g, &lds[buf][mat][u * 4096 + w * 512]); // wave-uniform base + lane*16
    };

    // prologue: B(0), A(0), B(1) -- 12 units; vmcnt(4) leaves only B(1) in flight
#pragma unroll
    for (int u = 0; u < 4; ++u) stage(1, u, 0, 0);
#pragma unroll
    for (int u = 0; u < 4; ++u) stage(0, u, 0, 0);
    if (NT > 1) {
#pragma unroll
        for (int u = 0; u < 4; ++u) stage(1, u, BK, 1);
        asm volatile("s_waitcnt vmcnt(4)" ::: "memory");
    } else {
        asm volatile("s_waitcnt vmcnt(0)" ::: "memory");
    }
    __builtin_amdgcn_s_barrier();
    __builtin_amdgcn_sched_barrier(0);

    for (int tt = 0; tt < NT; ++tt) {
        const int cur = tt & 1, nxt = cur ^ 1;
        const int kt1 = (tt + 1) * BK, kt2 = (tt + 2) * BK;
        short8 bfr[4][2];
#pragma unroll
        for (int p = 0; p < 4; ++p) {
            short8 af[2][2];
            if (p == 0) {
#pragma unroll
                for (int ni = 0; ni < 4; ++ni)
#pragma unroll
                    for (int kk = 0; kk < 2; ++kk) {
                        const int rb = wc * 64 + ni * 16 + lr;
                        const int j = kk * 4 + lq;
                        bfr[ni][kk] = *(const short8*)&lds[cur][1][rb * 64 + ((j ^ (rb & 7)) << 3)];
                    }
            }
#pragma unroll
            for (int mi2 = 0; mi2 < 2; ++mi2)
#pragma unroll
                for (int kk = 0; kk < 2; ++kk) {
                    const int ra = wr * 128 + (2 * p + mi2) * 16 + lr;
                    const int j = kk * 4 + lq;
                    af[mi2][kk] = *(const short8*)&lds[cur][0][ra * 64 + ((j ^ (ra & 7)) << 3)];
                }
            if (p == 0 && tt + 1 < NT) { stage(0, 0, kt1, nxt); stage(0, 1, kt1, nxt); }
            if (p == 1 && tt + 1 < NT) { stage(0, 2, kt1, nxt); stage(0, 3, kt1, nxt); }
            if (p == 2 && tt + 2 < NT) { stage(1, 0, kt2, cur); stage(1, 1, kt2, cur); }
            if (p == 3 && tt + 2 < NT) { stage(1, 2, kt2, cur); stage(1, 3, kt2, cur); }

            __builtin_amdgcn_sched_barrier(0);
            __builtin_amdgcn_s_barrier();
            __builtin_amdgcn_sched_barrier(0);
            __builtin_amdgcn_s_setprio(1);
#pragma unroll
            for (int kk = 0; kk < 2; ++kk)
#pragma unroll
                for (int mi2 = 0; mi2 < 2; ++mi2)
#pragma unroll
                    for (int ni = 0; ni < 4; ++ni)
                        acc[2 * p + mi2][ni] = __builtin_amdgcn_mfma_f32_16x16x32_bf16(
                            af[mi2][kk], bfr[ni][kk], acc[2 * p + mi2][ni], 0, 0, 0);
            __builtin_amdgcn_s_setprio(0);
            __builtin_amdgcn_sched_barrier(0);
            if (p == 3) {
                if (tt < NT - 2) asm volatile("s_waitcnt vmcnt(4)" ::: "memory");
                else             asm volatile("s_waitcnt vmcnt(0)" ::: "memory");
            }
            __builtin_amdgcn_s_barrier();
            __builtin_amdgcn_sched_barrier(0);
        }
    }

    // epilogue: D row = (lane>>4)*4 + reg, col = lane&15
#pragma unroll
    for (int mi = 0; mi < 8; ++mi) {
#pragma unroll
        for (int ni = 0; ni < 4; ++ni) {
            const size_t col = n0 + wc * 64 + ni * 16 + lr;
            const float cb = (bias_mode == 1) ? bias[col] : 0.f;
            floatx4 v = acc[mi][ni];
#pragma unroll
            for (int r = 0; r < 4; ++r) {
                const size_t row = m0 + wr * 128 + mi * 16 + lq * 4 + r;
                float val = v[r] * scale + cb;
                if (bias_mode == 2) val += bias[row];
                if (OUT_BF16)
                    ((unsigned short*)O)[(size_t)z * oBS + row * (size_t)ldo + col] = f2bf(val);
                else
                    ((float*)O)[(size_t)z * oBS + row * (size_t)ldo + col] = val;
            }
        }
    }
}

// fp32 -> bf16 vectorized conversion, grid-stride
__global__ void cvt_f2b(const float4* __restrict__ src, ushort4* __restrict__ dst, int n4)
{
    int i = blockIdx.x * blockDim.x + threadIdx.x;
    const int stride = gridDim.x * blockDim.x;
    for (; i < n4; i += stride) {
        float4 f = src[i];
        dst[i] = (ushort4){f2bf(f.x), f2bf(f.y), f2bf(f.z), f2bf(f.w)};
    }
}

// One wave per row of S (2048 fp32): add mask, fp32 softmax, write P bf16 in
// place over the row's own fp32 storage (bf16 row stride = 4096 elements).
__global__ void softmax_kernel(float* __restrict__ S, const float* __restrict__ mask, int b0)
{
    const int lane = threadIdx.x & 63;
    const int wid = threadIdx.x >> 6;
    const size_t rowid = (size_t)blockIdx.x * 4 + wid;
    const size_t bi = rowid >> 11;
    const size_t q = rowid & 2047;
    float* Srow = S + rowid * 2048;
    const float* Mrow = mask + (((size_t)b0 + bi) * 2048 + q) * 2048;

    float4 v[8];
    float mx = -3.4e38f;
#pragma unroll
    for (int i = 0; i < 8; ++i) {
        float4 s = ((const float4*)Srow)[i * 64 + lane];
        float4 m = ((const float4*)Mrow)[i * 64 + lane];
        s.x += m.x; s.y += m.y; s.z += m.z; s.w += m.w;
        v[i] = s;
        mx = fmaxf(mx, fmaxf(fmaxf(s.x, s.y), fmaxf(s.z, s.w)));
    }
#pragma unroll
    for (int off = 32; off; off >>= 1) mx = fmaxf(mx, __shfl_xor(mx, off, 64));
    float sum = 0.f;
#pragma unroll
    for (int i = 0; i < 8; ++i) {
        v[i].x = __expf(v[i].x - mx);
        v[i].y = __expf(v[i].y - mx);
        v[i].z = __expf(v[i].z - mx);
        v[i].w = __expf(v[i].w - mx);
        sum += v[i].x + v[i].y + v[i].z + v[i].w;
    }
#pragma unroll
    for (int off = 32; off; off >>= 1) sum += __shfl_xor(sum, off, 64);
    const float inv = 1.0f / sum;

    unsigned short* Prow = (unsigned short*)Srow;
#pragma unroll
    for (int i = 0; i < 8; ++i) {
        ushort4 h = {f2bf(v[i].x * inv), f2bf(v[i].y * inv),
                     f2bf(v[i].z * inv), f2bf(v[i].w * inv)};
        ((ushort4*)Prow)[i * 64 + lane] = h;
    }
}

extern "C" void kernel_launch(void* const* d_in, const int* in_sizes, int n_in,
                              void* d_out, int out_size, void* d_ws, size_t ws_size,
                              hipStream_t stream)
{
    const float* x    = (const float*)d_in[0];
    const float* mask = (const float*)d_in[1];
    const float* Wq   = (const float*)d_in[2];
    const float* bq   = (const float*)d_in[3];
    const float* Wk   = (const float*)d_in[4];
    const float* bk   = (const float*)d_in[5];
    const float* Wv   = (const float*)d_in[6];
    const float* bv   = (const float*)d_in[7];
    float* out = (float*)d_out;

    const size_t MB = 1ull << 20;
    char* ws = (char*)d_ws;
    unsigned short* Qb  = (unsigned short*)(ws);             // 16384x1024 bf16 (32MB)
    unsigned short* Kb  = (unsigned short*)(ws + 32 * MB);   // 16384x1024 bf16
    unsigned short* Vt  = (unsigned short*)(ws + 64 * MB);   // 1024x16384 bf16 (V^T)
    unsigned short* Wqb = (unsigned short*)(ws + 96 * MB);   // 1024x1024 bf16 (2MB)
    unsigned short* Wkb = (unsigned short*)(ws + 98 * MB);
    unsigned short* Wvb = (unsigned short*)(ws + 100 * MB);
    unsigned short* xb  = (unsigned short*)(ws + 102 * MB);  // 16384x1024 bf16, dead after proj
    float* Sb = (float*)(ws + 102 * MB);                     // S overlays xb region onward

    size_t savail = (ws_size > 102 * MB) ? ws_size - 102 * MB : 0;
    int g = 1;
    if (savail >= 128 * MB) g = 8;
    else if (savail >= 64 * MB) g = 4;
    else if (savail >= 32 * MB) g = 2;

    dim3 blk(512, 1, 1);

    cvt_f2b<<<2048, 256, 0, stream>>>((const float4*)x, (ushort4*)xb, 16384 * 1024 / 4);
    cvt_f2b<<<512, 256, 0, stream>>>((const float4*)Wq, (ushort4*)Wqb, 1024 * 1024 / 4);
    cvt_f2b<<<512, 256, 0, stream>>>((const float4*)Wk, (ushort4*)Wkb, 1024 * 1024 / 4);
    cvt_f2b<<<512, 256, 0, stream>>>((const float4*)Wv, (ushort4*)Wvb, 1024 * 1024 / 4);

    // Q = x @ Wq^T + bq : M=16384 (64 bx), N=1024 (4 by)
    gemm_bt<true><<<dim3(256, 1, 1), blk, 0, stream>>>(
        xb, Wqb, Qb, bq, 1, 1024, 1024, 1024, 1024, 0LL, 0LL, 0LL, 1.0f, 4);
    // K = x @ Wk^T + bk
    gemm_bt<true><<<dim3(256, 1, 1), blk, 0, stream>>>(
        xb, Wkb, Kb, bk, 1, 1024, 1024, 1024, 1024, 0LL, 0LL, 0LL, 1.0f, 4);
    // V^T = Wv @ x^T + bv : M=1024 (4 bx), N=16384 (64 by), per-row bias
    gemm_bt<true><<<dim3(256, 1, 1), blk, 0, stream>>>(
        Wvb, xb, Vt, bv, 2, 1024, 1024, 1024, 16384, 0LL, 0LL, 0LL, 1.0f, 64);

    const float sscale = 0.03125f; // 1/sqrt(1024)
    for (int b0 = 0; b0 < 8; b0 += g) {
        const int gb = (8 - b0 < g) ? (8 - b0) : g;
        // S = (Q @ K^T) * scale : per batch M=N=2048 (8x8), z = gb
        gemm_bt<false><<<dim3(64, 1, gb), blk, 0, stream>>>(
            Qb + (size_t)b0 * 2048 * 1024, Kb + (size_t)b0 * 2048 * 1024, Sb,
            (const float*)nullptr, 0, 1024, 1024, 1024, 2048,
            2048LL * 1024, 2048LL * 1024, 2048LL * 2048, sscale, 8);
        softmax_kernel<<<dim3(gb * 512, 1, 1), dim3(256), 0, stream>>>(Sb, mask, b0);
        // O = P @ V : M=2048 (8), N=1024 (4), K=2048
        gemm_bt<false><<<dim3(32, 1, gb), blk, 0, stream>>>(
            (const unsigned short*)Sb, Vt + (size_t)b0 * 2048,
            out + (size_t)b0 * 2048 * 1024, (const float*)nullptr, 0,
            2048, 4096, 16384, 1024,
            2048LL * 4096, 2048LL, 2048LL * 1024, 1.0f, 4);
    }
}

// Round 7
// 506.030 us; speedup vs baseline: 1.7486x; 1.1007x over previous
//
#include <hip/hip_runtime.h>
#include <hip/hip_bf16.h>
#include <hip/hip_fp16.h>

typedef __attribute__((ext_vector_type(8))) short short8;
typedef __attribute__((ext_vector_type(4))) short sh4;
typedef __attribute__((ext_vector_type(8))) _Float16 half8;
typedef __attribute__((ext_vector_type(4))) float floatx4;

__device__ __forceinline__ unsigned short f2bf(float f) {
    unsigned int u = __builtin_bit_cast(unsigned int, f);
    u += 0x7fffu + ((u >> 16) & 1u);
    return (unsigned short)(u >> 16);
}

__device__ __forceinline__ void gl_lds16(const unsigned short* g, unsigned short* l) {
    __builtin_amdgcn_global_load_lds(
        (const __attribute__((address_space(1))) unsigned int*)(const void*)g,
        (__attribute__((address_space(3))) unsigned int*)(void*)l,
        16, 0, 0);
}

#define BM 256
#define BN 256
#define BK 64

// C = A @ B^T, A (M,K) lda, B (N,K) ldb, bf16 K-contiguous row-major.
// 256x256 8-phase template (round-6 verified: 0 bank conflicts): 8 waves (2Mx4N),
// BK=64, 128KB dbuf LDS, counted vmcnt(4), chunk XOR-swizzle both-sides.
// OMODE: 0=bf16 out, 1=fp32 out, 2=fp16 out.
// Fused-projection extras: bias1!=null selects bias/cshift by col region (1024-wide);
// vstart>=0 marks N-region written TRANSPOSED to Vt (per-wave LDS transpose).
template<int OMODE>
__global__ __launch_bounds__(512, 2)
void gemm_bt(const unsigned short* __restrict__ A,
             const unsigned short* __restrict__ B,
             void* __restrict__ O,
             const float* __restrict__ bias0, const float* __restrict__ bias1,
             const float* __restrict__ bias2,
             int K, int lda, int ldb, int ldo,
             long long aBS, long long bBS, long long oBS,
             float scale, int nby, int vstart,
             unsigned short* __restrict__ Vt, int ldvt)
{
    __shared__ __align__(16) unsigned short lds[2][2][BM * BK]; // 128 KiB

    const int t = threadIdx.x;
    const int lane = t & 63;
    const int w = t >> 6;
    const int wr = w >> 2;       // 0..1 (M)
    const int wc = w & 3;        // 0..3 (N)
    const int lq = lane >> 4;
    const int lr = lane & 15;

    // T1: bijective XCD swizzle (grid.x % 8 == 0 everywhere here)
    const int nwg = gridDim.x;
    const int swz = (blockIdx.x & 7) * (nwg >> 3) + (blockIdx.x >> 3);
    const int by = swz % nby, bx = swz / nby;
    const size_t m0 = (size_t)bx * BM, n0 = (size_t)by * BN;

    const int z = blockIdx.z;
    const unsigned short* Az = A + (size_t)z * aBS;
    const unsigned short* Bz = B + (size_t)z * bBS;

    const int srow = t >> 3;
    const int scol = ((t & 7) ^ (srow & 7)) << 3;

    floatx4 acc[8][4];
#pragma unroll
    for (int i = 0; i < 8; ++i)
#pragma unroll
        for (int j = 0; j < 4; ++j)
            acc[i][j] = (floatx4){0.f, 0.f, 0.f, 0.f};

    const int NT = K / BK;

    auto stage = [&](int mat, int u, int kt, int buf) {
        const unsigned short* g = (mat ? Bz + (n0 + u * 64 + srow) * (size_t)ldb
                                       : Az + (m0 + u * 64 + srow) * (size_t)lda) + kt + scol;
        gl_lds16(g, &lds[buf][mat][u * 4096 + w * 512]);
    };

#pragma unroll
    for (int u = 0; u < 4; ++u) stage(1, u, 0, 0);
#pragma unroll
    for (int u = 0; u < 4; ++u) stage(0, u, 0, 0);
    if (NT > 1) {
#pragma unroll
        for (int u = 0; u < 4; ++u) stage(1, u, BK, 1);
        asm volatile("s_waitcnt vmcnt(4)" ::: "memory");
    } else {
        asm volatile("s_waitcnt vmcnt(0)" ::: "memory");
    }
    __builtin_amdgcn_s_barrier();
    __builtin_amdgcn_sched_barrier(0);

    for (int tt = 0; tt < NT; ++tt) {
        const int cur = tt & 1, nxt = cur ^ 1;
        const int kt1 = (tt + 1) * BK, kt2 = (tt + 2) * BK;
        short8 bfr[4][2];
#pragma unroll
        for (int p = 0; p < 4; ++p) {
            short8 af[2][2];
            if (p == 0) {
#pragma unroll
                for (int ni = 0; ni < 4; ++ni)
#pragma unroll
                    for (int kk = 0; kk < 2; ++kk) {
                        const int rb = wc * 64 + ni * 16 + lr;
                        const int j = kk * 4 + lq;
                        bfr[ni][kk] = *(const short8*)&lds[cur][1][rb * 64 + ((j ^ (rb & 7)) << 3)];
                    }
            }
#pragma unroll
            for (int mi2 = 0; mi2 < 2; ++mi2)
#pragma unroll
                for (int kk = 0; kk < 2; ++kk) {
                    const int ra = wr * 128 + (2 * p + mi2) * 16 + lr;
                    const int j = kk * 4 + lq;
                    af[mi2][kk] = *(const short8*)&lds[cur][0][ra * 64 + ((j ^ (ra & 7)) << 3)];
                }
            if (p == 0 && tt + 1 < NT) { stage(0, 0, kt1, nxt); stage(0, 1, kt1, nxt); }
            if (p == 1 && tt + 1 < NT) { stage(0, 2, kt1, nxt); stage(0, 3, kt1, nxt); }
            if (p == 2 && tt + 2 < NT) { stage(1, 0, kt2, cur); stage(1, 1, kt2, cur); }
            if (p == 3 && tt + 2 < NT) { stage(1, 2, kt2, cur); stage(1, 3, kt2, cur); }

            __builtin_amdgcn_sched_barrier(0);
            __builtin_amdgcn_s_barrier();
            __builtin_amdgcn_sched_barrier(0);
            __builtin_amdgcn_s_setprio(1);
#pragma unroll
            for (int kk = 0; kk < 2; ++kk)
#pragma unroll
                for (int mi2 = 0; mi2 < 2; ++mi2)
#pragma unroll
                    for (int ni = 0; ni < 4; ++ni)
                        acc[2 * p + mi2][ni] = __builtin_amdgcn_mfma_f32_16x16x32_bf16(
                            af[mi2][kk], bfr[ni][kk], acc[2 * p + mi2][ni], 0, 0, 0);
            __builtin_amdgcn_s_setprio(0);
            __builtin_amdgcn_sched_barrier(0);
            if (p == 3) {
                if (tt < NT - 2) asm volatile("s_waitcnt vmcnt(4)" ::: "memory");
                else             asm volatile("s_waitcnt vmcnt(0)" ::: "memory");
            }
            __builtin_amdgcn_s_barrier();
            __builtin_amdgcn_sched_barrier(0);
        }
    }

    // region-based bias select (fused projection only)
    const float* bias = bias0; int cshift = 0;
    if (bias1) {
        const int r = (int)(n0 >> 10);
        bias = (r == 0) ? bias0 : ((r == 1) ? bias1 : bias2);
        cshift = r << 10;
    }

    if (vstart >= 0 && (int)n0 >= vstart) {
        // Transposed write -> Vt[col - vstart][row], via per-wave 16KB LDS tile.
        // LDS layout: elem = tc*128 + (tr ^ ((tc&7)<<3))  (XOR kills bank conflicts)
        unsigned short* lf = &lds[0][0][0] + w * 8192;
        __syncthreads(); // staging LDS dead after final K-loop barrier (block-uniform branch)
#pragma unroll
        for (int mi = 0; mi < 8; ++mi) {
#pragma unroll
            for (int ni = 0; ni < 4; ++ni) {
                const int tc = ni * 16 + lr;                    // 0..63 (wave-local col)
                const int col = (int)n0 + wc * 64 + tc;
                const float cb = bias ? bias[col - cshift] : 0.f;
                const int tr0 = mi * 16 + lq * 4;               // 0..124 (wave-local row)
                floatx4 v = acc[mi][ni];
                sh4 pk;
#pragma unroll
                for (int r = 0; r < 4; ++r) pk[r] = (short)f2bf(v[r] * scale + cb);
                *(sh4*)&lf[tc * 128 + (tr0 ^ ((tc & 7) << 3))] = pk;
            }
        }
        __syncthreads();
        const int vrow_base = (int)n0 - vstart + wc * 64;
        const size_t colb = m0 + (size_t)wr * 128 + (size_t)(lane & 15) * 8;
#pragma unroll
        for (int i = 0; i < 16; ++i) {
            const int vr = i * 4 + (lane >> 4);
            short8 d = *(const short8*)&lf[vr * 128 + (((lane & 15) * 8) ^ ((vr & 7) << 3))];
            *(short8*)&Vt[(size_t)(vrow_base + vr) * ldvt + colb] = d;
        }
    } else {
        // normal epilogue: D row = (lane>>4)*4 + reg, col = lane&15
#pragma unroll
        for (int mi = 0; mi < 8; ++mi) {
#pragma unroll
            for (int ni = 0; ni < 4; ++ni) {
                const size_t col = n0 + wc * 64 + ni * 16 + lr;
                const float cb = bias ? bias[col - cshift] : 0.f;
                floatx4 v = acc[mi][ni];
#pragma unroll
                for (int r = 0; r < 4; ++r) {
                    const size_t row = m0 + wr * 128 + mi * 16 + lq * 4 + r;
                    const float val = v[r] * scale + cb;
                    const size_t off = (size_t)z * oBS + row * (size_t)ldo + col;
                    if (OMODE == 0)
                        ((unsigned short*)O)[off] = f2bf(val);
                    else if (OMODE == 1)
                        ((float*)O)[off] = val;
                    else {
                        _Float16 h = (_Float16)val;
                        ((unsigned short*)O)[off] = __builtin_bit_cast(unsigned short, h);
                    }
                }
            }
        }
    }
}

// fp32 -> bf16 for 4 segments (x, Wq, Wk, Wv) in one grid-stride launch
__global__ void cvt4(const float4* __restrict__ s0, ushort4* __restrict__ d0, int n0,
                     const float4* __restrict__ s1, ushort4* __restrict__ d1, int n1,
                     const float4* __restrict__ s2, ushort4* __restrict__ d2, int n2,
                     const float4* __restrict__ s3, ushort4* __restrict__ d3, int n3)
{
    const int total = n0 + n1 + n2 + n3;
    const int stride = gridDim.x * blockDim.x;
    for (int i = blockIdx.x * blockDim.x + threadIdx.x; i < total; i += stride) {
        const float4* s; ushort4* d; int j = i;
        if (j < n0) { s = s0; d = d0; }
        else { j -= n0;
            if (j < n1) { s = s1; d = d1; }
            else { j -= n1;
                if (j < n2) { s = s2; d = d2; }
                else { j -= n2; s = s3; d = d3; }
            }
        }
        float4 f = s[j];
        d[j] = (ushort4){f2bf(f.x), f2bf(f.y), f2bf(f.z), f2bf(f.w)};
    }
}

// One wave per row: S fp16 (2048) + mask fp32 -> fp32 softmax -> P bf16 in place.
__global__ void softmax_kernel(_Float16* __restrict__ S, const float* __restrict__ mask, int b0)
{
    const int lane = threadIdx.x & 63;
    const int wid = threadIdx.x >> 6;
    const size_t rowid = (size_t)blockIdx.x * 4 + wid;
    const size_t bi = rowid >> 11;
    const size_t q = rowid & 2047;
    _Float16* Srow = S + rowid * 2048;
    const float* Mrow = mask + (((size_t)b0 + bi) * 2048 + q) * 2048;

    float v[32];
    float mx = -3.4e38f;
#pragma unroll
    for (int i = 0; i < 4; ++i) {
        half8 h = ((const half8*)Srow)[i * 64 + lane];
        float4 ma = ((const float4*)Mrow)[i * 128 + lane * 2];
        float4 mb = ((const float4*)Mrow)[i * 128 + lane * 2 + 1];
        const float* mp0 = (const float*)&ma;
        const float* mp1 = (const float*)&mb;
#pragma unroll
        for (int j = 0; j < 4; ++j) {
            v[i * 8 + j]     = (float)h[j]     + mp0[j];
            v[i * 8 + 4 + j] = (float)h[4 + j] + mp1[j];
        }
#pragma unroll
        for (int j = 0; j < 8; ++j) mx = fmaxf(mx, v[i * 8 + j]);
    }
#pragma unroll
    for (int off = 32; off; off >>= 1) mx = fmaxf(mx, __shfl_xor(mx, off, 64));
    float sum = 0.f;
#pragma unroll
    for (int i = 0; i < 32; ++i) { v[i] = __expf(v[i] - mx); sum += v[i]; }
#pragma unroll
    for (int off = 32; off; off >>= 1) sum += __shfl_xor(sum, off, 64);
    const float inv = 1.0f / sum;

    unsigned short* Prow = (unsigned short*)Srow;
#pragma unroll
    for (int i = 0; i < 4; ++i) {
        short8 pk;
#pragma unroll
        for (int j = 0; j < 8; ++j) pk[j] = (short)f2bf(v[i * 8 + j] * inv);
        ((short8*)Prow)[i * 64 + lane] = pk;
    }
}

extern "C" void kernel_launch(void* const* d_in, const int* in_sizes, int n_in,
                              void* d_out, int out_size, void* d_ws, size_t ws_size,
                              hipStream_t stream)
{
    const float* x    = (const float*)d_in[0];
    const float* mask = (const float*)d_in[1];
    const float* Wq   = (const float*)d_in[2];
    const float* bq   = (const float*)d_in[3];
    const float* Wk   = (const float*)d_in[4];
    const float* bk   = (const float*)d_in[5];
    const float* Wv   = (const float*)d_in[6];
    const float* bv   = (const float*)d_in[7];
    float* out = (float*)d_out;

    const size_t MB = 1ull << 20;
    char* ws = (char*)d_ws;
    unsigned short* QKb  = (unsigned short*)(ws);             // 16384 x 2048 bf16 (Q cols 0-1023, K cols 1024-2047), 64MB
    unsigned short* Vt   = (unsigned short*)(ws + 64 * MB);   // 1024 x 16384 bf16 (V^T), 32MB
    unsigned short* Wcat = (unsigned short*)(ws + 96 * MB);   // 3072 x 1024 bf16 [Wq;Wk;Wv], 6MB
    unsigned short* xb   = (unsigned short*)(ws + 102 * MB);  // 16384 x 1024 bf16, 32MB
    _Float16* Sb         = (_Float16*)(ws + 134 * MB);        // g x 2048 x 2048 fp16 (P bf16 in place)

    size_t savail = (ws_size > 134 * MB) ? ws_size - 134 * MB : 0;
    int g = (int)(savail / (8 * MB));
    if (g < 1) g = 1;
    if (g > 8) g = 8;

    // fp32 -> bf16 (x + the three weights) in one launch
    cvt4<<<2048, 256, 0, stream>>>(
        (const float4*)x,  (ushort4*)xb,               16384 * 1024 / 4,
        (const float4*)Wq, (ushort4*)Wcat,             1024 * 1024 / 4,
        (const float4*)Wk, (ushort4*)(Wcat + 1048576), 1024 * 1024 / 4,
        (const float4*)Wv, (ushort4*)(Wcat + 2097152), 1024 * 1024 / 4);

    // Fused QKV projection: M=16384, N=3072, K=1024. Cols 0-2047 -> QKb rows;
    // cols 2048-3071 -> transposed into Vt (per-row bias handled as per-col here).
    gemm_bt<0><<<dim3(768, 1, 1), dim3(512), 0, stream>>>(
        xb, Wcat, QKb, bq, bk, bv,
        1024, 1024, 1024, 2048, 0LL, 0LL, 0LL, 1.0f, 12, 2048, Vt, 16384);

    const float sscale = 0.03125f; // 1/sqrt(1024)
    for (int b0 = 0; b0 < 8; b0 += g) {
        const int gb = (8 - b0 < g) ? (8 - b0) : g;
        // S = (Q @ K^T) * scale -> fp16, per batch M=N=2048
        gemm_bt<2><<<dim3(64, 1, gb), dim3(512), 0, stream>>>(
            QKb + (size_t)b0 * 4194304, QKb + 1024 + (size_t)b0 * 4194304, Sb,
            nullptr, nullptr, nullptr,
            1024, 2048, 2048, 2048,
            4194304LL, 4194304LL, 4194304LL, sscale, 8, -1, nullptr, 0);
        // softmax rows (+mask), P bf16 in place (row stride 2048)
        softmax_kernel<<<dim3(gb * 512), dim3(256), 0, stream>>>(Sb, mask, b0);
        // O = P @ V : M=2048, N=1024, K=2048 (B = Vt rows, K-contiguous)
        gemm_bt<1><<<dim3(32, 1, gb), dim3(512), 0, stream>>>(
            (const unsigned short*)(void*)Sb, Vt + (size_t)b0 * 2048,
            out + (size_t)b0 * 2048 * 1024,
            nullptr, nullptr, nullptr,
            2048, 2048, 16384, 1024,
            4194304LL, 2048LL, 2097152LL, 1.0f, 4, -1, nullptr, 0);
    }
}